// Round 14
// baseline (117.285 us; speedup 1.0000x reference)
//
#include <hip/hip_runtime.h>
#include <hip/hip_bf16.h>
#include <stdint.h>

// RNDiscriminator: B=64, d^2=64 positions, 26 features, g: 52->256->256, f: 256->1
// h1[i,j] = relu(u'[j] + v[i]); dominant cost sum_ij relu(h1 @ W2 + b2) = 34.4 GF bf16.
//
// R14: REGISTER-BUILT A-FRAGMENTS -- h1 never touches LDS. Each wave owns a
// 32x64 C-tile: u-slice resident as packed bf16 (upk[2][8][4], 64 VGPR),
// Bf[8][4] resident (128), acc[2][4] (32). Per pair: v slices broadcast-read
// from 16KB LDS, A-frags built in regs (~450 VALU, hidden under 128 MFMAs),
// no barriers/flags/ring in the pair loop. 256 blocks x 512 thr, 2 waves/SIMD.

typedef float f32x4 __attribute__((ext_vector_type(4)));
typedef float f32x2 __attribute__((ext_vector_type(2)));
typedef short short8 __attribute__((ext_vector_type(8)));
typedef int   int4v  __attribute__((ext_vector_type(4)));

__device__ __forceinline__ uint32_t cvt_pk_bf16(float lo, float hi) {
    uint32_t r;
    asm("v_cvt_pk_bf16_f32 %0, %1, %2" : "=v"(r) : "v"(lo), "v"(hi));
    return r;
}
__device__ __forceinline__ f32x2 relu2(f32x2 a) {
    f32x2 z = (f32x2){0.f, 0.f};
    return __builtin_elementwise_max(a, z);
}
// h1 pair from packed-bf16 u + f32 v: relu(u+v) -> packed bf16
__device__ __forceinline__ uint32_t fuse2(uint32_t up, float vlo, float vhi) {
    f32x2 uu;
    uu.x = __uint_as_float(up << 16);
    uu.y = __uint_as_float(up & 0xFFFF0000u);
    f32x2 r = relu2(uu + (f32x2){vlo, vhi});
    return cvt_pk_bf16(r.x, r.y);
}

// K12: blocks 0..255: fused conv(8x8/s8)+relu+coords -> u,v rows.
//      blocks 256..287: pre-fragment W2 (bf16, fragment-major).
__global__ void k12_front(const float* __restrict__ img, const float* __restrict__ cw,
                          const float* __restrict__ cb, const float* __restrict__ w1,
                          const float* __restrict__ b1, const float* __restrict__ w2,
                          float* __restrict__ u, float* __restrict__ v,
                          short* __restrict__ w2f) {
    int g = blockIdx.x;
    int t = threadIdx.x;
    if (g >= 256) {
        int fi = (g - 256) * 4 + (t >> 6);
        int l = t & 63;
        int ks = fi >> 4, ni2 = fi & 15;
        int n  = ni2 * 16 + (l & 15);
        int k0 = ks * 32 + (l >> 4) * 8;
        float f[8];
        #pragma unroll
        for (int e = 0; e < 8; ++e) f[e] = w2[(k0 + e) * 256 + n];
        union { short8 s; uint32_t w[4]; } A;
        A.w[0] = cvt_pk_bf16(f[0], f[1]);
        A.w[1] = cvt_pk_bf16(f[2], f[3]);
        A.w[2] = cvt_pk_bf16(f[4], f[5]);
        A.w[3] = cvt_pk_bf16(f[6], f[7]);
        *(short8*)(w2f + (fi * 64 + l) * 8) = A.s;
        return;
    }
    __shared__ float xs[16][26];
    int b = g >> 2, q = g & 3, p0 = q * 16;

    for (int idx = t; idx < 416; idx += 256) {
        int pl = idx / 26;
        int ch = idx - pl * 26;
        int pos = p0 + pl;
        int r = pos >> 3, c = pos & 7;
        float val;
        if (ch < 24) {
            float s = cb[ch];
            #pragma unroll
            for (int ci = 0; ci < 3; ++ci)
                #pragma unroll
                for (int kr = 0; kr < 8; ++kr) {
                    const float* ip = img + ((b * 3 + ci) * 64 + r * 8 + kr) * 64 + c * 8;
                    const float* wp = cw + ((ch * 3 + ci) * 8 + kr) * 8;
                    #pragma unroll
                    for (int kc = 0; kc < 8; ++kc) s += ip[kc] * wp[kc];
                }
            val = fmaxf(s, 0.f);
        } else if (ch == 24) {
            val = -1.f + (2.f / 7.f) * (float)c;
        } else {
            val = -1.f + (2.f / 7.f) * (float)r;
        }
        xs[pl][ch] = val;
    }
    __syncthreads();

    // phase 2, k-outer (w1 loads hoisted)
    int c = t;
    float bc = b1[c];
    float su[16], sv[16];
    #pragma unroll
    for (int r = 0; r < 16; ++r) { su[r] = bc; sv[r] = 0.f; }
    #pragma unroll 2
    for (int k = 0; k < 26; ++k) {
        float wu = w1[k * 256 + c];
        float wv2 = w1[(26 + k) * 256 + c];
        #pragma unroll
        for (int r = 0; r < 16; ++r) {
            float xv = xs[r][k];
            su[r] += xv * wu;
            sv[r] += xv * wv2;
        }
    }
    #pragma unroll
    for (int r = 0; r < 16; ++r) {
        int bj = b * 64 + p0 + r;
        u[bj * 256 + c] = su[r];
        v[bj * 256 + c] = sv[r];
    }
}

// ---- k3 macros (all indices literal -- rule #20) ----
#define BUILD_FRAG(DST, MI, KS, V0, V1)                                \
    { int4v d_;                                                        \
      d_.x = fuse2(upk[MI][KS][0], (V0).x, (V0).y);                    \
      d_.y = fuse2(upk[MI][KS][1], (V0).z, (V0).w);                    \
      d_.z = fuse2(upk[MI][KS][2], (V1).x, (V1).y);                    \
      d_.w = fuse2(upk[MI][KS][3], (V1).z, (V1).w);                    \
      DST = *(short8*)&d_; }

#define KSTEP(KS)                                                      \
    { f32x4 V0 = *(const f32x4*)(vq + (KS) * 32 + lg8);                \
      f32x4 V1 = *(const f32x4*)(vq + (KS) * 32 + lg8 + 4);            \
      short8 a0, a1;                                                   \
      BUILD_FRAG(a0, 0, KS, V0, V1)                                    \
      BUILD_FRAG(a1, 1, KS, V0, V1)                                    \
      acc[0][0] = __builtin_amdgcn_mfma_f32_16x16x32_bf16(a0, Bf[KS][0], acc[0][0], 0,0,0); \
      acc[1][0] = __builtin_amdgcn_mfma_f32_16x16x32_bf16(a1, Bf[KS][0], acc[1][0], 0,0,0); \
      acc[0][1] = __builtin_amdgcn_mfma_f32_16x16x32_bf16(a0, Bf[KS][1], acc[0][1], 0,0,0); \
      acc[1][1] = __builtin_amdgcn_mfma_f32_16x16x32_bf16(a1, Bf[KS][1], acc[1][1], 0,0,0); \
      acc[0][2] = __builtin_amdgcn_mfma_f32_16x16x32_bf16(a0, Bf[KS][2], acc[0][2], 0,0,0); \
      acc[1][2] = __builtin_amdgcn_mfma_f32_16x16x32_bf16(a1, Bf[KS][2], acc[1][2], 0,0,0); \
      acc[0][3] = __builtin_amdgcn_mfma_f32_16x16x32_bf16(a0, Bf[KS][3], acc[0][3], 0,0,0); \
      acc[1][3] = __builtin_amdgcn_mfma_f32_16x16x32_bf16(a1, Bf[KS][3], acc[1][3], 0,0,0); }

__global__ __launch_bounds__(512, 2) void k3_pairs(
        const float* __restrict__ u, const float* __restrict__ v,
        const short* __restrict__ w2f, const float* __restrict__ b2,
        float* __restrict__ part) {
    __shared__ float vs[16][256];        // 16 KB -- the ONLY LDS
    int t = threadIdx.x;
    int lane = t & 63, wv = t >> 6;      // wv 0..7
    int lr = lane & 15, lg = lane >> 4;
    int lg8 = lg * 8;
    int blk = blockIdx.x;                // 0..255
    int b = blk & 63, i0 = (blk >> 6) * 16;
    int wr = wv & 1, wc = wv >> 1;       // rows wr*32..+32, cols wc*64..+64
    int r0 = wr * 32;

    // stage the 16 v rows once (vs[q][k]), 8 floats/thread
    {
        int q = t >> 5, c8 = (t & 31) * 8;
        const float* vr = v + (b * 64 + i0 + q) * 256 + c8;
        *(float4*)&vs[q][c8]     = *(const float4*)vr;
        *(float4*)&vs[q][c8 + 4] = *(const float4*)(vr + 4);
    }

    // resident B fragments: cols wc*64 + cg*16 (static indices only)
    short8 Bf[8][4];
    #pragma unroll
    for (int ks = 0; ks < 8; ++ks)
        #pragma unroll
        for (int cg = 0; cg < 4; ++cg)
            Bf[ks][cg] = *(const short8*)(w2f + ((ks * 16 + wc * 4 + cg) * 64 + lane) * 8);

    float bias[4];
    #pragma unroll
    for (int cg = 0; cg < 4; ++cg) bias[cg] = b2[wc * 64 + cg * 16 + lr];

    // u-slice resident as packed bf16: rows r0 + mi*16 + lr, k = ks*32+lg*8 ..+8
    uint32_t upk[2][8][4];
    {
        const float* ur0 = u + (b * 64 + r0 + lr) * 256 + lg8;
        const float* ur1 = ur0 + 16 * 256;
        #pragma unroll
        for (int ks = 0; ks < 8; ++ks) {
            f32x4 x0 = *(const f32x4*)(ur0 + ks * 32);
            f32x4 x1 = *(const f32x4*)(ur0 + ks * 32 + 4);
            f32x4 y0 = *(const f32x4*)(ur1 + ks * 32);
            f32x4 y1 = *(const f32x4*)(ur1 + ks * 32 + 4);
            upk[0][ks][0] = cvt_pk_bf16(x0.x, x0.y);
            upk[0][ks][1] = cvt_pk_bf16(x0.z, x0.w);
            upk[0][ks][2] = cvt_pk_bf16(x1.x, x1.y);
            upk[0][ks][3] = cvt_pk_bf16(x1.z, x1.w);
            upk[1][ks][0] = cvt_pk_bf16(y0.x, y0.y);
            upk[1][ks][1] = cvt_pk_bf16(y0.z, y0.w);
            upk[1][ks][2] = cvt_pk_bf16(y1.x, y1.y);
            upk[1][ks][3] = cvt_pk_bf16(y1.z, y1.w);
        }
    }
    __syncthreads();             // vs ready (only barrier in the kernel)

    float csum[4] = {0.f, 0.f, 0.f, 0.f};

    #pragma unroll 1
    for (int q = 0; q < 16; ++q) {
        const float* vq = &vs[q][0];

        f32x4 acc[2][4];
        #pragma unroll
        for (int mi = 0; mi < 2; ++mi)
            #pragma unroll
            for (int cg = 0; cg < 4; ++cg) acc[mi][cg] = (f32x4){0.f, 0.f, 0.f, 0.f};

        KSTEP(0) KSTEP(1) KSTEP(2) KSTEP(3)
        KSTEP(4) KSTEP(5) KSTEP(6) KSTEP(7)

        // epilogue: relu(C + b2) partial column-sum over this wave's 32 rows
        #pragma unroll
        for (int cg = 0; cg < 4; ++cg) {
            float s = csum[cg];
            #pragma unroll
            for (int mi = 0; mi < 2; ++mi)
                #pragma unroll
                for (int r = 0; r < 4; ++r)
                    s += fmaxf(acc[mi][cg][r] + bias[cg], 0.f);
            csum[cg] = s;
        }
    }

    // flush: reduce over lg groups; lanes 0-15 store this wave's 64-col partial
    #pragma unroll
    for (int cg = 0; cg < 4; ++cg) {
        float s = csum[cg];
        s += __shfl_xor(s, 16);
        s += __shfl_xor(s, 32);
        if (lane < 16) part[(blk * 8 + wv) * 64 + cg * 16 + lr] = s;
    }
}

// K5: pooled[b][c] = sum over 4 i-quarters x 2 row-halves; then f-head.
__global__ void k5_head(const float* __restrict__ part, const float* __restrict__ fw1,
                        const float* __restrict__ fb1, const float* __restrict__ fw2,
                        const float* __restrict__ fb2, float* __restrict__ out) {
    __shared__ float P[256];
    __shared__ float wsum[4];
    int b = blockIdx.x, t = threadIdx.x;
    int wc = t >> 6, cl = t & 63;
    float s0 = 0.f;
    #pragma unroll
    for (int g = 0; g < 4; ++g) {
        const float* p = part + ((b + 64 * g) * 8 + wc * 2) * 64 + cl;
        s0 += p[0] + p[64];     // wr = 0, 1
    }
    P[t] = s0;
    __syncthreads();
    float a0 = 0.f, a1 = 0.f, a2 = 0.f, a3 = 0.f;
    for (int k = 0; k < 64; ++k) {
        a0 += P[k]       * fw1[k * 256 + t];
        a1 += P[k + 64]  * fw1[(k + 64) * 256 + t];
        a2 += P[k + 128] * fw1[(k + 128) * 256 + t];
        a3 += P[k + 192] * fw1[(k + 192) * 256 + t];
    }
    float h = fmaxf(fb1[t] + a0 + a1 + a2 + a3, 0.f);
    float p = h * fw2[t];
    #pragma unroll
    for (int off = 32; off >= 1; off >>= 1) p += __shfl_xor(p, off);
    if ((t & 63) == 0) wsum[t >> 6] = p;
    __syncthreads();
    if (t == 0) out[b] = wsum[0] + wsum[1] + wsum[2] + wsum[3] + fb2[0];
}

extern "C" void kernel_launch(void* const* d_in, const int* in_sizes, int n_in,
                              void* d_out, int out_size, void* d_ws, size_t ws_size,
                              hipStream_t stream) {
    const float* image  = (const float*)d_in[0];
    const float* conv_w = (const float*)d_in[1];
    const float* conv_b = (const float*)d_in[2];
    const float* g_w1   = (const float*)d_in[3];
    const float* g_b1   = (const float*)d_in[4];
    const float* g_w2   = (const float*)d_in[5];
    const float* g_b2   = (const float*)d_in[6];
    const float* f_w1   = (const float*)d_in[7];
    const float* f_b1   = (const float*)d_in[8];
    const float* f_w2   = (const float*)d_in[9];
    const float* f_b2   = (const float*)d_in[10];
    float* out = (float*)d_out;

    char* ws = (char*)d_ws;
    float* u    = (float*)(ws + 0);          // 64*64*256*4 = 4 MB
    float* v    = (float*)(ws + 4194304);    // 4 MB
    short* w2f  = (short*)(ws + 8388608);    // 128 KB
    float* part = (float*)(ws + 8519680);    // 256*8*64*4 = 512 KB

    k12_front<<<288, 256, 0, stream>>>(image, conv_w, conv_b, g_w1, g_b1, g_w2,
                                       u, v, w2f);
    k3_pairs<<<256, 512, 0, stream>>>(u, v, w2f, g_b2, part);
    k5_head<<<64, 256, 0, stream>>>(part, f_w1, f_b1, f_w2, f_b2, out);
}

// Round 15
// 60.254 us; speedup vs baseline: 1.9465x; 1.9465x over previous
//
#include <hip/hip_runtime.h>
#include <hip/hip_bf16.h>
#include <stdint.h>

// RNDiscriminator: B=64, d^2=64 positions, 26 features, g: 52->256->256, f: 256->1
// h1[i,j] = relu(u'[j] + v[i]); dominant cost sum_ij relu(h1 @ W2 + b2) = 34.4 GF bf16.
//
// R15: 3 waves/SIMD role-split P/C + fragment-major h1 (zero-conflict LDS).
// 256 blocks x 768 thr (12 waves): waves 0-3 = producers (1/SIMD, u packed-bf16
// in 32 VGPR, build h1 frags in regs, write frag-major: fid*1024 + lane*16 --
// lane-contiguous, NO swizzle, NO conflicts). Waves 4-11 = consumers (2/SIMD,
// cols wc*32: Bf[8][2]=64, acc[4][2]=32 AGPR, contiguous A-frag reads).
// Flag-synced 4-deep ring, no barriers in pair loop. Two consumers per SIMD
// cover each other's LDS latency on the matrix pipe.

typedef float f32x4 __attribute__((ext_vector_type(4)));
typedef float f32x2 __attribute__((ext_vector_type(2)));
typedef short short8 __attribute__((ext_vector_type(8)));
typedef int   int4v  __attribute__((ext_vector_type(4)));

#define NB 4   // ring depth

__device__ __forceinline__ uint32_t cvt_pk_bf16(float lo, float hi) {
    uint32_t r;
    asm("v_cvt_pk_bf16_f32 %0, %1, %2" : "=v"(r) : "v"(lo), "v"(hi));
    return r;
}
__device__ __forceinline__ f32x2 relu2(f32x2 a) {
    f32x2 z = (f32x2){0.f, 0.f};
    return __builtin_elementwise_max(a, z);
}
// h1 pair from packed-bf16 u + f32 v: relu(u+v) -> packed bf16
__device__ __forceinline__ uint32_t fuse2(uint32_t up, float vlo, float vhi) {
    f32x2 uu;
    uu.x = __uint_as_float(up << 16);
    uu.y = __uint_as_float(up & 0xFFFF0000u);
    f32x2 r = relu2(uu + (f32x2){vlo, vhi});
    return cvt_pk_bf16(r.x, r.y);
}
__device__ __forceinline__ void spin_eq(int* p, int val) {
    while (__hip_atomic_load(p, __ATOMIC_ACQUIRE, __HIP_MEMORY_SCOPE_WORKGROUP) != val)
        __builtin_amdgcn_s_sleep(1);
    __builtin_amdgcn_sched_barrier(0);
}
__device__ __forceinline__ void flag_release_add(int* p, int lane) {
    asm volatile("s_waitcnt lgkmcnt(0)" ::: "memory");
    if (lane == 0)
        __hip_atomic_fetch_add(p, 1, __ATOMIC_RELEASE, __HIP_MEMORY_SCOPE_WORKGROUP);
}

// K12: blocks 0..255: fused conv(8x8/s8)+relu+coords -> u,v rows.
//      blocks 256..287: pre-fragment W2 (bf16, fragment-major).
__global__ void k12_front(const float* __restrict__ img, const float* __restrict__ cw,
                          const float* __restrict__ cb, const float* __restrict__ w1,
                          const float* __restrict__ b1, const float* __restrict__ w2,
                          float* __restrict__ u, float* __restrict__ v,
                          short* __restrict__ w2f) {
    int g = blockIdx.x;
    int t = threadIdx.x;
    if (g >= 256) {
        int fi = (g - 256) * 4 + (t >> 6);
        int l = t & 63;
        int ks = fi >> 4, ni2 = fi & 15;
        int n  = ni2 * 16 + (l & 15);
        int k0 = ks * 32 + (l >> 4) * 8;
        float f[8];
        #pragma unroll
        for (int e = 0; e < 8; ++e) f[e] = w2[(k0 + e) * 256 + n];
        union { short8 s; uint32_t w[4]; } A;
        A.w[0] = cvt_pk_bf16(f[0], f[1]);
        A.w[1] = cvt_pk_bf16(f[2], f[3]);
        A.w[2] = cvt_pk_bf16(f[4], f[5]);
        A.w[3] = cvt_pk_bf16(f[6], f[7]);
        *(short8*)(w2f + (fi * 64 + l) * 8) = A.s;
        return;
    }
    __shared__ float xs[16][26];
    int b = g >> 2, q = g & 3, p0 = q * 16;

    for (int idx = t; idx < 416; idx += 256) {
        int pl = idx / 26;
        int ch = idx - pl * 26;
        int pos = p0 + pl;
        int r = pos >> 3, c = pos & 7;
        float val;
        if (ch < 24) {
            float s = cb[ch];
            #pragma unroll
            for (int ci = 0; ci < 3; ++ci)
                #pragma unroll
                for (int kr = 0; kr < 8; ++kr) {
                    const float* ip = img + ((b * 3 + ci) * 64 + r * 8 + kr) * 64 + c * 8;
                    const float* wp = cw + ((ch * 3 + ci) * 8 + kr) * 8;
                    #pragma unroll
                    for (int kc = 0; kc < 8; ++kc) s += ip[kc] * wp[kc];
                }
            val = fmaxf(s, 0.f);
        } else if (ch == 24) {
            val = -1.f + (2.f / 7.f) * (float)c;
        } else {
            val = -1.f + (2.f / 7.f) * (float)r;
        }
        xs[pl][ch] = val;
    }
    __syncthreads();

    int c = t;
    float bc = b1[c];
    float su[16], sv[16];
    #pragma unroll
    for (int r = 0; r < 16; ++r) { su[r] = bc; sv[r] = 0.f; }
    #pragma unroll 2
    for (int k = 0; k < 26; ++k) {
        float wu = w1[k * 256 + c];
        float wv2 = w1[(26 + k) * 256 + c];
        #pragma unroll
        for (int r = 0; r < 16; ++r) {
            float xv = xs[r][k];
            su[r] += xv * wu;
            sv[r] += xv * wv2;
        }
    }
    #pragma unroll
    for (int r = 0; r < 16; ++r) {
        int bj = b * 64 + p0 + r;
        u[bj * 256 + c] = su[r];
        v[bj * 256 + c] = sv[r];
    }
}

// ---- consumer macros: frag-major A reads (contiguous, conflict-free) ----
#define C_READ(A, KS)                                                  \
    { A[0] = *(const short8*)(cb0 + (KS) * 1024);                      \
      A[1] = *(const short8*)(cb0 + 8192  + (KS) * 1024);              \
      A[2] = *(const short8*)(cb0 + 16384 + (KS) * 1024);              \
      A[3] = *(const short8*)(cb0 + 24576 + (KS) * 1024); }

#define C_MFMA(A, KS)                                                  \
    { acc[0][0] = __builtin_amdgcn_mfma_f32_16x16x32_bf16(A[0], Bf[KS][0], acc[0][0], 0,0,0); \
      acc[1][0] = __builtin_amdgcn_mfma_f32_16x16x32_bf16(A[1], Bf[KS][0], acc[1][0], 0,0,0); \
      acc[2][0] = __builtin_amdgcn_mfma_f32_16x16x32_bf16(A[2], Bf[KS][0], acc[2][0], 0,0,0); \
      acc[3][0] = __builtin_amdgcn_mfma_f32_16x16x32_bf16(A[3], Bf[KS][0], acc[3][0], 0,0,0); \
      acc[0][1] = __builtin_amdgcn_mfma_f32_16x16x32_bf16(A[0], Bf[KS][1], acc[0][1], 0,0,0); \
      acc[1][1] = __builtin_amdgcn_mfma_f32_16x16x32_bf16(A[1], Bf[KS][1], acc[1][1], 0,0,0); \
      acc[2][1] = __builtin_amdgcn_mfma_f32_16x16x32_bf16(A[2], Bf[KS][1], acc[2][1], 0,0,0); \
      acc[3][1] = __builtin_amdgcn_mfma_f32_16x16x32_bf16(A[3], Bf[KS][1], acc[3][1], 0,0,0); }

__global__ __launch_bounds__(768, 3) void k3_pairs(
        const float* __restrict__ u, const float* __restrict__ v,
        const short* __restrict__ w2f, const float* __restrict__ b2,
        float* __restrict__ part) {
    __shared__ short h1s[NB][64 * 256];   // 128 KB ring, fragment-major slots
    __shared__ float vs[16][256];         // 16 KB
    __shared__ int prod_cnt[16];
    __shared__ int cons_cnt[16];
    int t = threadIdx.x;
    int lane = t & 63, wv = t >> 6;       // wv 0..11
    int lr = lane & 15, lg = lane >> 4;
    int blk = blockIdx.x;                 // 0..255
    int b = blk & 63, i0 = (blk >> 6) * 16;

    if (t < 16) { prod_cnt[t] = 0; cons_cnt[t] = 0; }

    // stage the 16 v rows once (threads 0..511)
    if (t < 512) {
        int q = t >> 5, c8 = (t & 31) * 8;
        const float* vr = v + (b * 64 + i0 + q) * 256 + c8;
        *(float4*)&vs[q][c8]     = *(const float4*)vr;
        *(float4*)&vs[q][c8 + 4] = *(const float4*)(vr + 4);
    }

    if (wv < 4) {
        // ========== PRODUCER (waves 0-3, one per SIMD) ==========
        // thread owns 8 lane-frags: fid = j*4 + wv; holds u packed-bf16 (32 VGPR)
        uint32_t upk[8][4];
        #pragma unroll
        for (int j = 0; j < 8; ++j) {
            int fid = j * 4 + wv;
            int row = (fid >> 3) * 16 + lr;
            int k0 = (fid & 7) * 32 + lg * 8;
            const float* up = u + (b * 64 + row) * 256 + k0;
            f32x4 x0 = *(const f32x4*)up;
            f32x4 x1 = *(const f32x4*)(up + 4);
            upk[j][0] = cvt_pk_bf16(x0.x, x0.y);
            upk[j][1] = cvt_pk_bf16(x0.z, x0.w);
            upk[j][2] = cvt_pk_bf16(x1.x, x1.y);
            upk[j][3] = cvt_pk_bf16(x1.z, x1.w);
        }
        __syncthreads();   // vs ready; flags init'd

        #pragma unroll 1
        for (int q = 0; q < 16; ++q) {
            if (q >= NB) spin_eq(&cons_cnt[q - NB], 8);
            char* base = (char*)h1s[q & (NB - 1)] + lane * 16;
            #pragma unroll
            for (int j = 0; j < 8; ++j) {
                int fid = j * 4 + wv;
                int k0 = (fid & 7) * 32 + lg * 8;
                f32x4 v0 = *(const f32x4*)&vs[q][k0];
                f32x4 v1 = *(const f32x4*)&vs[q][k0 + 4];
                int4v d;
                d.x = (int)fuse2(upk[j][0], v0.x, v0.y);
                d.y = (int)fuse2(upk[j][1], v0.z, v0.w);
                d.z = (int)fuse2(upk[j][2], v1.x, v1.y);
                d.w = (int)fuse2(upk[j][3], v1.z, v1.w);
                *(int4v*)(base + fid * 1024) = d;
            }
            flag_release_add(&prod_cnt[q], lane);
        }
    } else {
        // ========== CONSUMER (waves 4-11, two per SIMD) ==========
        int wc = wv - 4;                  // cols wc*32 .. +32

        short8 Bf[8][2];
        #pragma unroll
        for (int ks = 0; ks < 8; ++ks)
            #pragma unroll
            for (int cg = 0; cg < 2; ++cg)
                Bf[ks][cg] = *(const short8*)(w2f + ((ks * 16 + wc * 2 + cg) * 64 + lane) * 8);

        float bias[2];
        #pragma unroll
        for (int cg = 0; cg < 2; ++cg) bias[cg] = b2[wc * 32 + cg * 16 + lr];

        float csum[2] = {0.f, 0.f};
        __syncthreads();   // vs ready; flags init'd

        #pragma unroll 1
        for (int q = 0; q < 16; ++q) {
            spin_eq(&prod_cnt[q], 4);
            const char* cb0 = (const char*)h1s[q & (NB - 1)] + lane * 16;

            f32x4 acc[4][2];
            #pragma unroll
            for (int mi = 0; mi < 4; ++mi)
                #pragma unroll
                for (int cg = 0; cg < 2; ++cg) acc[mi][cg] = (f32x4){0.f, 0.f, 0.f, 0.f};

            short8 Aa[4], Ab[4];
            C_READ(Aa, 0) C_READ(Ab, 1)
            __builtin_amdgcn_s_setprio(1);
            C_MFMA(Aa, 0) C_READ(Aa, 2)
            C_MFMA(Ab, 1) C_READ(Ab, 3)
            C_MFMA(Aa, 2) C_READ(Aa, 4)
            C_MFMA(Ab, 3) C_READ(Ab, 5)
            C_MFMA(Aa, 4) C_READ(Aa, 6)
            C_MFMA(Ab, 5) C_READ(Ab, 7)
            C_MFMA(Aa, 6)
            C_MFMA(Ab, 7)
            __builtin_amdgcn_s_setprio(0);

            // epilogue: relu(C + b2) partial column-sum
            #pragma unroll
            for (int cg = 0; cg < 2; ++cg) {
                float s = 0.f;
                #pragma unroll
                for (int mi = 0; mi < 4; ++mi)
                    #pragma unroll
                    for (int r = 0; r < 4; ++r)
                        s += fmaxf(acc[mi][cg][r] + bias[cg], 0.f);
                csum[cg] += s;
            }
            flag_release_add(&cons_cnt[q], lane);
        }

        // flush: reduce over lg groups; lanes 0-15 store this wave's 32-col partial
        #pragma unroll
        for (int cg = 0; cg < 2; ++cg) {
            float s = csum[cg];
            s += __shfl_xor(s, 16);
            s += __shfl_xor(s, 32);
            if (lane < 16) part[(blk * 8 + wc) * 32 + cg * 16 + lr] = s;
        }
    }
}

// K5: pooled[b][c] = sum over 4 i-quarter blocks; then f-head.
__global__ void k5_head(const float* __restrict__ part, const float* __restrict__ fw1,
                        const float* __restrict__ fb1, const float* __restrict__ fw2,
                        const float* __restrict__ fb2, float* __restrict__ out) {
    __shared__ float P[256];
    __shared__ float wsum[4];
    int b = blockIdx.x, t = threadIdx.x;
    int wc = t >> 5, cl = t & 31;
    float s0 = 0.f;
    #pragma unroll
    for (int g = 0; g < 4; ++g)
        s0 += part[((b + 64 * g) * 8 + wc) * 32 + cl];
    P[t] = s0;
    __syncthreads();
    float a0 = 0.f, a1 = 0.f, a2 = 0.f, a3 = 0.f;
    for (int k = 0; k < 64; ++k) {
        a0 += P[k]       * fw1[k * 256 + t];
        a1 += P[k + 64]  * fw1[(k + 64) * 256 + t];
        a2 += P[k + 128] * fw1[(k + 128) * 256 + t];
        a3 += P[k + 192] * fw1[(k + 192) * 256 + t];
    }
    float h = fmaxf(fb1[t] + a0 + a1 + a2 + a3, 0.f);
    float p = h * fw2[t];
    #pragma unroll
    for (int off = 32; off >= 1; off >>= 1) p += __shfl_xor(p, off);
    if ((t & 63) == 0) wsum[t >> 6] = p;
    __syncthreads();
    if (t == 0) out[b] = wsum[0] + wsum[1] + wsum[2] + wsum[3] + fb2[0];
}

extern "C" void kernel_launch(void* const* d_in, const int* in_sizes, int n_in,
                              void* d_out, int out_size, void* d_ws, size_t ws_size,
                              hipStream_t stream) {
    const float* image  = (const float*)d_in[0];
    const float* conv_w = (const float*)d_in[1];
    const float* conv_b = (const float*)d_in[2];
    const float* g_w1   = (const float*)d_in[3];
    const float* g_b1   = (const float*)d_in[4];
    const float* g_w2   = (const float*)d_in[5];
    const float* g_b2   = (const float*)d_in[6];
    const float* f_w1   = (const float*)d_in[7];
    const float* f_b1   = (const float*)d_in[8];
    const float* f_w2   = (const float*)d_in[9];
    const float* f_b2   = (const float*)d_in[10];
    float* out = (float*)d_out;

    char* ws = (char*)d_ws;
    float* u    = (float*)(ws + 0);          // 64*64*256*4 = 4 MB
    float* v    = (float*)(ws + 4194304);    // 4 MB
    short* w2f  = (short*)(ws + 8388608);    // 128 KB
    float* part = (float*)(ws + 8519680);    // 256*8*32*4 = 256 KB

    k12_front<<<288, 256, 0, stream>>>(image, conv_w, conv_b, g_w1, g_b1, g_w2,
                                       u, v, w2f);
    k3_pairs<<<256, 768, 0, stream>>>(u, v, w2f, g_b2, part);
    k5_head<<<64, 256, 0, stream>>>(part, f_w1, f_b1, f_w2, f_b2, out);
}